// Round 9
// baseline (766.852 us; speedup 1.0000x reference)
//
#include <hip/hip_runtime.h>

#define N_NODES 65536
#define IN_FEAT 16
#define HIDDEN 32
#define NUM_EDGES 1048576
#define NUM_GRAPHS 16
#define NODES_PER_GRAPH 4096
#define FC1_IN (NODES_PER_GRAPH * HIDDEN) /* 131072 */
#define FC1_OUT 256
#define FC2_OUT 64
#define FC1_KCHUNK 128
#define FC1_BLOCKS (FC1_IN / FC1_KCHUNK) /* 1024 */
#define RED_Q 16        /* reduce fan-in groups */
#define NB 256          /* buckets = dst>>8 */
#define BUCKET_CAP 5120 /* binned: mean 4096, sd 64 -> 16 sigma headroom */
#define CSR_CAP 8192    /* csr: 4096 + row-align pad + headroom */
#define EPB_A 4096      /* edges per phase-A block */
#define NREP 8          /* measurement round: 8x internal repeat on idempotent kernels */

typedef _Float16 half8 __attribute__((ext_vector_type(8)));         // 16 B
typedef float floatx4 __attribute__((ext_vector_type(4)));          // native vec for nt builtins
typedef unsigned short ushort8 __attribute__((ext_vector_type(8))); // 16 B

__device__ __forceinline__ float4 ntload4(const float4* p) {
    floatx4 v = __builtin_nontemporal_load((const floatx4*)p);
    return make_float4(v.x, v.y, v.z, v.w);
}
__device__ __forceinline__ void ntstore4(float4* p, float4 v) {
    floatx4 w = {v.x, v.y, v.z, v.w};
    __builtin_nontemporal_store(w, (floatx4*)p);
}
__device__ __forceinline__ int ntloadi(const int* p) {
    return __builtin_nontemporal_load(p);
}
__device__ __forceinline__ float ntloadf(const float* p) {
    return __builtin_nontemporal_load(p);
}

// ---- init bucket cursors to fixed-capacity bases ----
__global__ void initcur_kernel(int* __restrict__ bucket_cursor) {
    bucket_cursor[threadIdx.x] = threadIdx.x * BUCKET_CAP;
}

// ---- phase A: bin edges by dst>>8 (NOT repeated: cursor atomics not idempotent) ----
__global__ void binA_kernel(const int* __restrict__ src, const int* __restrict__ dst,
                            int* __restrict__ bucket_cursor, int* __restrict__ binned) {
    __shared__ int hist[NB];
    __shared__ int base[NB];
    __shared__ int cur[NB];
    int t = threadIdx.x;
    hist[t] = 0;
    __syncthreads();
    int e0 = blockIdx.x * EPB_A;
    int s[16], d[16];
#pragma unroll
    for (int i = 0; i < 16; i++) {
        int e = e0 + t + 256 * i;
        s[i] = ntloadi(src + e);
        d[i] = ntloadi(dst + e);
    }
#pragma unroll
    for (int i = 0; i < 16; i++) atomicAdd(&hist[d[i] >> 8], 1);
    __syncthreads();
    base[t] = atomicAdd(&bucket_cursor[t], hist[t]);
    cur[t] = 0;
    __syncthreads();
#pragma unroll
    for (int i = 0; i < 16; i++) {
        int b = d[i] >> 8;
        int r = atomicAdd(&cur[b], 1);
        binned[base[b] + r] = s[i] | ((d[i] & 255) << 16);
    }
}

// ---- phase B: per-bucket counting sort; REPEATED 8x (idempotent) ----
__global__ void sortB_kernel(const int* __restrict__ bucket_cursor, const int* __restrict__ binned,
                             unsigned short* __restrict__ csr, int* __restrict__ rowstart,
                             int* __restrict__ rowend, float* __restrict__ dinv,
                             const float* __restrict__ x, half8* __restrict__ p0) {
    __shared__ int hist[NB];
    __shared__ int scanbuf[NB];
    __shared__ int start[NB];
    __shared__ int cur[NB];
    int t = threadIdx.x;  // 0..511
    int b = blockIdx.x;
    int bbase = b * BUCKET_CAP;
    int cbase = b * CSR_CAP;
    for (int rep = 0; rep < NREP; ++rep) {
        __syncthreads();  // protect LDS reinit across reps
        int cnt = bucket_cursor[b] - bbase;
        if (t < NB) hist[t] = 0;
        __syncthreads();
        for (int i = t; i < cnt; i += 512) atomicAdd(&hist[binned[bbase + i] >> 16], 1);
        __syncthreads();
        int v = 0;
        if (t < NB) {
            v = hist[t];
            scanbuf[t] = (v + 7) & ~7;  // padded row size -> 16B-aligned starts
        }
        __syncthreads();
        for (int off = 1; off < NB; off <<= 1) {
            int y = 0;
            if (t < NB && t >= off) y = scanbuf[t - off];
            __syncthreads();
            if (t < NB) scanbuf[t] += y;
            __syncthreads();
        }
        if (t < NB) {
            start[t] = scanbuf[t] - ((v + 7) & ~7);
            cur[t] = 0;
        }
        __syncthreads();
        for (int i = t; i < cnt; i += 512) {
            int p = binned[bbase + i];
            int dl = p >> 16;
            int r = atomicAdd(&cur[dl], 1);
            csr[cbase + start[dl] + r] = (unsigned short)(p & 0xFFFF);
        }
        if (t < NB) {
            int n = b * NB + t;
            int excl = start[t];
            rowstart[n] = cbase + excl;
            rowend[n] = cbase + excl + v;
            dinv[n] = rsqrtf((float)v + 1.0f);
        }
        {
            int nl = t >> 1;
            int qq = t & 1;
            int n = b * NB + nl;
            float di = rsqrtf((float)hist[nl] + 1.0f);
            const float4* x4 = (const float4*)x;
            float4 a = x4[(size_t)n * 4 + 2 * qq];
            float4 c = x4[(size_t)n * 4 + 2 * qq + 1];
            half8 hh;
            hh[0] = (_Float16)(a.x * di); hh[1] = (_Float16)(a.y * di);
            hh[2] = (_Float16)(a.z * di); hh[3] = (_Float16)(a.w * di);
            hh[4] = (_Float16)(c.x * di); hh[5] = (_Float16)(c.y * di);
            hh[6] = (_Float16)(c.z * di); hh[7] = (_Float16)(c.w * di);
            p0[(size_t)n * 2 + qq] = hh;
        }
    }
}

// ---- fused gather+matmul; REPEATED 8x (idempotent) ----
template <int FIN, bool LAST>
__global__ void gmm_kernel(const int* __restrict__ rowstart, const int* __restrict__ rowend,
                           const unsigned short* __restrict__ csr, const half8* __restrict__ p,
                           const float* __restrict__ W, const float* __restrict__ bias,
                           const float* __restrict__ dinv, void* __restrict__ outp) {
    constexpr int F8 = FIN / 8;
    constexpr int LOG2F8 = (FIN == 16) ? 1 : 2;
    constexpr int NOUT4 = 8 / F8;
    __shared__ float4 Ws4[FIN * 8];
    __shared__ float4 bs4[8];
    int t = threadIdx.x;
    for (int i = t; i < FIN * 8; i += 256) Ws4[i] = ((const float4*)W)[i];
    if (t < 8) bs4[t] = ((const float4*)bias)[t];
    __syncthreads();

    int f8 = t & (F8 - 1);
    int n = (blockIdx.x * 256 + t) >> LOG2F8;

    for (int rep = 0; rep < NREP; ++rep) {
        asm volatile("" ::: "memory");  // defeat cross-rep hoist/DSE
        half8 self = p[(size_t)n * F8 + f8];
        float acc[8];
#pragma unroll
        for (int e = 0; e < 8; e++) acc[e] = (float)self[e];
        int beg = rowstart[n];
        int end = rowend[n];
        int i = beg;
        for (; i + 8 <= end; i += 8) {
            ushort8 sv = *(const ushort8*)(csr + i);
            half8 a[8];
#pragma unroll
            for (int u = 0; u < 8; u++) a[u] = p[(size_t)sv[u] * F8 + f8];
#pragma unroll
            for (int u = 0; u < 8; u++)
#pragma unroll
                for (int e = 0; e < 8; e++) acc[e] += (float)a[u][e];
        }
        if (i + 4 <= end) {
            int s[4];
#pragma unroll
            for (int u = 0; u < 4; u++) s[u] = csr[i + u];
            half8 a[4];
#pragma unroll
            for (int u = 0; u < 4; u++) a[u] = p[(size_t)s[u] * F8 + f8];
#pragma unroll
            for (int u = 0; u < 4; u++)
#pragma unroll
                for (int e = 0; e < 8; e++) acc[e] += (float)a[u][e];
            i += 4;
        }
        for (; i < end; i++) {
            half8 a = p[(size_t)csr[i] * F8 + f8];
#pragma unroll
            for (int e = 0; e < 8; e++) acc[e] += (float)a[e];
        }

        float a1[8], a2[8], a3[8];
#pragma unroll
        for (int e = 0; e < 8; e++) a1[e] = __shfl_xor(acc[e], 1);
        if (F8 == 4) {
#pragma unroll
            for (int e = 0; e < 8; e++) a2[e] = __shfl_xor(acc[e], 2);
#pragma unroll
            for (int e = 0; e < 8; e++) a3[e] = __shfl_xor(a1[e], 2);
        }

        int fo0 = f8 * NOUT4;
        float4 o4[NOUT4];
#pragma unroll
        for (int j = 0; j < NOUT4; j++) o4[j] = make_float4(0.f, 0.f, 0.f, 0.f);

#define MM_CHUNK(AR, C)                                               \
    {                                                                 \
        int c_ = (C);                                                 \
        _Pragma("unroll") for (int e = 0; e < 8; e++) {               \
            int fi = c_ * 8 + e;                                      \
            float r = (AR)[e];                                        \
            _Pragma("unroll") for (int j = 0; j < NOUT4; j++) {       \
                float4 wv = Ws4[fi * 8 + fo0 + j];                    \
                o4[j].x += r * wv.x;                                  \
                o4[j].y += r * wv.y;                                  \
                o4[j].z += r * wv.z;                                  \
                o4[j].w += r * wv.w;                                  \
            }                                                         \
        }                                                             \
    }

        MM_CHUNK(acc, f8)
        MM_CHUNK(a1, f8 ^ 1)
        if (F8 == 4) {
            MM_CHUNK(a2, f8 ^ 2)
            MM_CHUNK(a3, f8 ^ 3)
        }
#undef MM_CHUNK

        float di = dinv[n];
        float4 v4[NOUT4];
#pragma unroll
        for (int j = 0; j < NOUT4; j++) {
            float4 bb = bs4[fo0 + j];
            float4 v;
            v.x = o4[j].x * di + bb.x;
            v.y = o4[j].y * di + bb.y;
            v.z = o4[j].z * di + bb.z;
            v.w = o4[j].w * di + bb.w;
            v.x = v.x > 0.f ? v.x : 0.f;
            v.y = v.y > 0.f ? v.y : 0.f;
            v.z = v.z > 0.f ? v.z : 0.f;
            v.w = v.w > 0.f ? v.w : 0.f;
            v4[j] = v;
        }
        if (LAST) {
            float4* o = (float4*)outp;
#pragma unroll
            for (int j = 0; j < NOUT4; j++) o[(size_t)n * 8 + fo0 + j] = v4[j];
        } else {
            half8* o = (half8*)outp;
#pragma unroll
            for (int pr = 0; pr < NOUT4 / 2; pr++) {
                float4 lo = v4[2 * pr], hi = v4[2 * pr + 1];
                half8 hh;
                hh[0] = (_Float16)(lo.x * di); hh[1] = (_Float16)(lo.y * di);
                hh[2] = (_Float16)(lo.z * di); hh[3] = (_Float16)(lo.w * di);
                hh[4] = (_Float16)(hi.x * di); hh[5] = (_Float16)(hi.y * di);
                hh[6] = (_Float16)(hi.z * di); hh[7] = (_Float16)(hi.w * di);
                o[(size_t)n * 4 + fo0 / 2 + pr] = hh;
            }
        }
    }
}

// ---- fc1 partials; REPEATED 8x (idempotent) ----
__global__ __launch_bounds__(256) void fc1_kernel(const float* __restrict__ h3,
                                                  const float* __restrict__ w,
                                                  float* __restrict__ part) {
    __shared__ float hs[NUM_GRAPHS * FC1_KCHUNK];
    int t = threadIdx.x;
    int kbase = blockIdx.x * FC1_KCHUNK;
    for (int rep = 0; rep < NREP; ++rep) {
        __syncthreads();  // protect hs re-stage across reps
        for (int i = t; i < NUM_GRAPHS * FC1_KCHUNK; i += 256) {
            int g = i >> 7;
            int kk = i & 127;
            hs[i] = ntloadf(h3 + (size_t)g * FC1_IN + kbase + kk);
        }
        __syncthreads();
        int kl = t & 3;
        int c = t >> 2;
        const float4* w4 = (const float4*)w;
        float4 acc[NUM_GRAPHS];
#pragma unroll
        for (int g = 0; g < NUM_GRAPHS; g++) acc[g] = make_float4(0.f, 0.f, 0.f, 0.f);

        float4 wa[8], wb[8];
#define LOADW(BUF, I0)                                                        \
    _Pragma("unroll") for (int u = 0; u < 8; u++)                             \
        (BUF)[u] = ntload4(&w4[(size_t)(kbase + kl + 4 * ((I0) + u)) * (FC1_OUT / 4) + c]);
#define COMPW(BUF, I0)                                                        \
    _Pragma("unroll") for (int u = 0; u < 8; u++) {                           \
        int kk = kl + 4 * ((I0) + u);                                         \
        _Pragma("unroll") for (int g = 0; g < NUM_GRAPHS; g++) {              \
            float hg = hs[g * FC1_KCHUNK + kk];                               \
            acc[g].x += hg * (BUF)[u].x;                                      \
            acc[g].y += hg * (BUF)[u].y;                                      \
            acc[g].z += hg * (BUF)[u].z;                                      \
            acc[g].w += hg * (BUF)[u].w;                                      \
        }                                                                     \
    }

        LOADW(wa, 0)
        LOADW(wb, 8)
        COMPW(wa, 0)
        LOADW(wa, 16)
        COMPW(wb, 8)
        LOADW(wb, 24)
        COMPW(wa, 16)
        COMPW(wb, 24)
#undef LOADW
#undef COMPW

#pragma unroll
        for (int g = 0; g < NUM_GRAPHS; g++) {
            acc[g].x += __shfl_xor(acc[g].x, 1);
            acc[g].y += __shfl_xor(acc[g].y, 1);
            acc[g].z += __shfl_xor(acc[g].z, 1);
            acc[g].w += __shfl_xor(acc[g].w, 1);
            acc[g].x += __shfl_xor(acc[g].x, 2);
            acc[g].y += __shfl_xor(acc[g].y, 2);
            acc[g].z += __shfl_xor(acc[g].z, 2);
            acc[g].w += __shfl_xor(acc[g].w, 2);
        }
        if (kl == 0) {
            float4* p4 = (float4*)part;
#pragma unroll
            for (int g = 0; g < NUM_GRAPHS; g++)
                ntstore4(&p4[(size_t)blockIdx.x * (NUM_GRAPHS * FC1_OUT / 4) + g * (FC1_OUT / 4) + c],
                         acc[g]);
        }
    }
}

// ---- reduce; REPEATED 8x (idempotent) ----
__global__ void reduce_kernel(const float* __restrict__ part, float* __restrict__ partial16) {
    int tid = blockIdx.x * 256 + threadIdx.x;
    int j = tid & 4095;
    int bq = tid >> 12;
    for (int rep = 0; rep < NREP; ++rep) {
        asm volatile("" ::: "memory");
        float s = 0.f;
#pragma unroll 8
        for (int u = 0; u < FC1_BLOCKS / RED_Q; u++)
            s += ntloadf(&part[(size_t)(bq * (FC1_BLOCKS / RED_Q) + u) * (NUM_GRAPHS * FC1_OUT) + j]);
        partial16[bq * (NUM_GRAPHS * FC1_OUT) + j] = s;
    }
}

// ---- fc2: folds the 16 partials, bias+relu, then 256->64 matmul ----
__global__ void fc2_kernel(const float* __restrict__ partial16, const float* __restrict__ fc1_b,
                           const float* __restrict__ w2, const float* __restrict__ b2,
                           float* __restrict__ out) {
    int g = blockIdx.x;
    int j = threadIdx.x;
    __shared__ float vs[FC1_OUT];
    for (int k = j; k < FC1_OUT; k += 64) {
        float s = fc1_b[k];
#pragma unroll
        for (int bq = 0; bq < RED_Q; bq++)
            s += partial16[bq * (NUM_GRAPHS * FC1_OUT) + g * FC1_OUT + k];
        vs[k] = s > 0.f ? s : 0.f;
    }
    __syncthreads();
    float acc = b2[j];
    for (int k = 0; k < FC1_OUT; k++) acc += vs[k] * w2[k * FC2_OUT + j];
    out[g * FC2_OUT + j] = acc;
}

extern "C" void kernel_launch(void* const* d_in, const int* in_sizes, int n_in,
                              void* d_out, int out_size, void* d_ws, size_t ws_size,
                              hipStream_t stream) {
    const float* x = (const float*)d_in[0];
    const int* ei = (const int*)d_in[1];
    const int* src = ei;
    const int* dst = ei + NUM_EDGES;
    const float* W1 = (const float*)d_in[2];
    const float* b1 = (const float*)d_in[3];
    const float* W2 = (const float*)d_in[4];
    const float* b2 = (const float*)d_in[5];
    const float* W3 = (const float*)d_in[6];
    const float* b3 = (const float*)d_in[7];
    const float* fc1_w = (const float*)d_in[8];
    const float* fc1_b = (const float*)d_in[9];
    const float* fc2_w = (const float*)d_in[10];
    const float* fc2_b = (const float*)d_in[11];
    float* out = (float*)d_out;

    int* bucket_cursor = (int*)d_ws;                       // 1 KB
    int* binned = bucket_cursor + 256;                     // 5.24 MB
    unsigned short* csr = (unsigned short*)(binned + NB * BUCKET_CAP);  // 4.19 MB
    int* rowstart = (int*)(csr + NB * CSR_CAP);            // 256 KB
    int* rowend = rowstart + N_NODES;                      // 256 KB
    float* dinv = (float*)(rowend + N_NODES);              // 256 KB
    half8* p0 = (half8*)(dinv + N_NODES);                  // 2 MB
    half8* pA = (half8*)(p0 + (size_t)N_NODES * 2);        // 4 MB
    half8* pB = (half8*)(pA + (size_t)N_NODES * 4);        // 4 MB
    float* h3 = (float*)(pB + (size_t)N_NODES * 4);        // 8 MB
    float* part = h3 + (size_t)N_NODES * HIDDEN;           // 16 MB
    float* partial16 = part + (size_t)FC1_BLOCKS * NUM_GRAPHS * FC1_OUT;  // 256 KB

    initcur_kernel<<<1, 256, 0, stream>>>(bucket_cursor);
    binA_kernel<<<NUM_EDGES / EPB_A, 256, 0, stream>>>(src, dst, bucket_cursor, binned);
    sortB_kernel<<<NB, 512, 0, stream>>>(bucket_cursor, binned, csr, rowstart, rowend, dinv, x, p0);

    gmm_kernel<IN_FEAT, false><<<N_NODES * 2 / 256, 256, 0, stream>>>(
        rowstart, rowend, csr, p0, W1, b1, dinv, pA);
    gmm_kernel<HIDDEN, false><<<N_NODES * 4 / 256, 256, 0, stream>>>(
        rowstart, rowend, csr, pA, W2, b2, dinv, pB);
    gmm_kernel<HIDDEN, true><<<N_NODES * 4 / 256, 256, 0, stream>>>(
        rowstart, rowend, csr, pB, W3, b3, dinv, h3);

    fc1_kernel<<<FC1_BLOCKS, 256, 0, stream>>>(h3, fc1_w, part);
    reduce_kernel<<<256, 256, 0, stream>>>(part, partial16);
    fc2_kernel<<<NUM_GRAPHS, 64, 0, stream>>>(partial16, fc1_b, fc2_w, fc2_b, out);
}

// Round 10
// 310.126 us; speedup vs baseline: 2.4727x; 2.4727x over previous
//
#include <hip/hip_runtime.h>

#define N_NODES 65536
#define IN_FEAT 16
#define HIDDEN 32
#define NUM_EDGES 1048576
#define NUM_GRAPHS 16
#define NODES_PER_GRAPH 4096
#define FC1_IN (NODES_PER_GRAPH * HIDDEN) /* 131072 */
#define FC1_OUT 256
#define FC2_OUT 64
#define FC1_KCHUNK 128
#define FC1_BLOCKS (FC1_IN / FC1_KCHUNK) /* 1024 */
#define RED_Q 16        /* reduce fan-in groups */
#define NB 256          /* buckets = dst>>8 */
#define BUCKET_CAP 5120 /* binned: mean 4096, sd 64 -> 16 sigma headroom */
#define CSR_CAP 8192    /* csr: 4096 + row-align pad + headroom */
#define EPB_A 2048      /* edges per phase-A block (512 blocks = 2/CU) */

typedef _Float16 half8 __attribute__((ext_vector_type(8)));         // 16 B
typedef float floatx4 __attribute__((ext_vector_type(4)));          // native vec for nt builtins
typedef unsigned short ushort8 __attribute__((ext_vector_type(8))); // 16 B

__device__ __forceinline__ float4 ntload4(const float4* p) {
    floatx4 v = __builtin_nontemporal_load((const floatx4*)p);
    return make_float4(v.x, v.y, v.z, v.w);
}
__device__ __forceinline__ int ntloadi(const int* p) {
    return __builtin_nontemporal_load(p);
}
__device__ __forceinline__ float ntloadf(const float* p) {
    return __builtin_nontemporal_load(p);
}

// ---- init bucket cursors to fixed-capacity bases ----
__global__ void initcur_kernel(int* __restrict__ bucket_cursor) {
    bucket_cursor[threadIdx.x] = threadIdx.x * BUCKET_CAP;
}

// ---- phase A: bin edges by dst>>8 with chunk-contiguous writes ----
// 512 blocks = 2 blocks/CU: double occupancy on the scatter phase.
__global__ void binA_kernel(const int* __restrict__ src, const int* __restrict__ dst,
                            int* __restrict__ bucket_cursor, int* __restrict__ binned) {
    __shared__ int hist[NB];
    __shared__ int base[NB];
    __shared__ int cur[NB];
    int t = threadIdx.x;
    hist[t] = 0;
    __syncthreads();
    int e0 = blockIdx.x * EPB_A;
    int s[8], d[8];
#pragma unroll
    for (int i = 0; i < 8; i++) {
        int e = e0 + t + 256 * i;
        s[i] = ntloadi(src + e);
        d[i] = ntloadi(dst + e);
    }
#pragma unroll
    for (int i = 0; i < 8; i++) atomicAdd(&hist[d[i] >> 8], 1);
    __syncthreads();
    base[t] = atomicAdd(&bucket_cursor[t], hist[t]);
    cur[t] = 0;
    __syncthreads();
#pragma unroll
    for (int i = 0; i < 8; i++) {
        int b = d[i] >> 8;
        int r = atomicAdd(&cur[b], 1);
        binned[base[b] + r] = s[i] | ((d[i] & 255) << 16);
    }
}

// ---- phase B: per-bucket LDS counting sort by dst low byte (1024 threads) ----
// emits csr (ushort, 16B-aligned row starts), rowstart/rowend, dinv, p0 = x*dinv fp16.
__global__ void sortB_kernel(const int* __restrict__ bucket_cursor, const int* __restrict__ binned,
                             unsigned short* __restrict__ csr, int* __restrict__ rowstart,
                             int* __restrict__ rowend, float* __restrict__ dinv,
                             const float* __restrict__ x, half8* __restrict__ p0) {
    __shared__ int hist[NB];
    __shared__ int scanbuf[NB];
    __shared__ int start[NB];
    __shared__ int cur[NB];
    int t = threadIdx.x;  // 0..1023
    int b = blockIdx.x;
    int bbase = b * BUCKET_CAP;
    int cbase = b * CSR_CAP;
    int cnt = bucket_cursor[b] - bbase;
    if (t < NB) hist[t] = 0;
    __syncthreads();
    for (int i = t; i < cnt; i += 1024) atomicAdd(&hist[binned[bbase + i] >> 16], 1);
    __syncthreads();
    int v = 0;
    if (t < NB) {
        v = hist[t];
        scanbuf[t] = (v + 7) & ~7;  // padded row size -> 16B-aligned starts
    }
    __syncthreads();
    for (int off = 1; off < NB; off <<= 1) {
        int y = 0;
        if (t < NB && t >= off) y = scanbuf[t - off];
        __syncthreads();
        if (t < NB) scanbuf[t] += y;
        __syncthreads();
    }
    if (t < NB) {
        start[t] = scanbuf[t] - ((v + 7) & ~7);  // exclusive prefix of padded sizes
        cur[t] = 0;
    }
    __syncthreads();
    for (int i = t; i < cnt; i += 1024) {
        int p = binned[bbase + i];
        int dl = p >> 16;
        int r = atomicAdd(&cur[dl], 1);
        csr[cbase + start[dl] + r] = (unsigned short)(p & 0xFFFF);
    }
    if (t < NB) {
        int n = b * NB + t;
        int excl = start[t];
        rowstart[n] = cbase + excl;
        rowend[n] = cbase + excl + v;
        dinv[n] = rsqrtf((float)v + 1.0f);
    }
    // p0 prescale: threads 0..511 = 256 nodes x 2 half8-chunks
    if (t < 512) {
        int nl = t >> 1;
        int qq = t & 1;
        int n = b * NB + nl;
        float di = rsqrtf((float)hist[nl] + 1.0f);
        const float4* x4 = (const float4*)x;
        float4 a = x4[(size_t)n * 4 + 2 * qq];
        float4 c = x4[(size_t)n * 4 + 2 * qq + 1];
        half8 hh;
        hh[0] = (_Float16)(a.x * di); hh[1] = (_Float16)(a.y * di);
        hh[2] = (_Float16)(a.z * di); hh[3] = (_Float16)(a.w * di);
        hh[4] = (_Float16)(c.x * di); hh[5] = (_Float16)(c.y * di);
        hh[6] = (_Float16)(c.z * di); hh[7] = (_Float16)(c.w * di);
        p0[(size_t)n * 2 + qq] = hh;
    }
}

// ---- fused gather+matmul, quad-grain (no mid-kernel block barrier) ----
template <int FIN, bool LAST>
__global__ void gmm_kernel(const int* __restrict__ rowstart, const int* __restrict__ rowend,
                           const unsigned short* __restrict__ csr, const half8* __restrict__ p,
                           const float* __restrict__ W, const float* __restrict__ bias,
                           const float* __restrict__ dinv, void* __restrict__ outp) {
    constexpr int F8 = FIN / 8;        // half8 chunks per input row: 2 or 4
    constexpr int LOG2F8 = (FIN == 16) ? 1 : 2;
    constexpr int NOUT4 = 8 / F8;      // float4 output groups per lane: 4 or 2
    __shared__ float4 Ws4[FIN * 8];    // W[FIN][32] as float4
    __shared__ float4 bs4[8];
    int t = threadIdx.x;
    for (int i = t; i < FIN * 8; i += 256) Ws4[i] = ((const float4*)W)[i];
    if (t < 8) bs4[t] = ((const float4*)bias)[t];
    __syncthreads();  // only barrier: before divergent work, no straggler cost

    int f8 = t & (F8 - 1);
    int n = (blockIdx.x * 256 + t) >> LOG2F8;

    // ---- gather stage ----
    half8 self = p[(size_t)n * F8 + f8];
    float acc[8];
#pragma unroll
    for (int e = 0; e < 8; e++) acc[e] = (float)self[e];
    int beg = rowstart[n];  // 16B-aligned (multiple of 8)
    int end = rowend[n];
    int i = beg;
    for (; i + 8 <= end; i += 8) {
        ushort8 sv = *(const ushort8*)(csr + i);  // single dwordx4 load
        half8 a[8];
#pragma unroll
        for (int u = 0; u < 8; u++) a[u] = p[(size_t)sv[u] * F8 + f8];
#pragma unroll
        for (int u = 0; u < 8; u++)
#pragma unroll
            for (int e = 0; e < 8; e++) acc[e] += (float)a[u][e];
    }
    if (i + 4 <= end) {
        int s[4];
#pragma unroll
        for (int u = 0; u < 4; u++) s[u] = csr[i + u];
        half8 a[4];
#pragma unroll
        for (int u = 0; u < 4; u++) a[u] = p[(size_t)s[u] * F8 + f8];
#pragma unroll
        for (int u = 0; u < 4; u++)
#pragma unroll
            for (int e = 0; e < 8; e++) acc[e] += (float)a[u][e];
        i += 4;
    }
    for (; i < end; i++) {
        half8 a = p[(size_t)csr[i] * F8 + f8];
#pragma unroll
        for (int e = 0; e < 8; e++) acc[e] += (float)a[e];
    }

    // ---- in-quad butterfly: lane gains all FIN q-features ----
    float a1[8], a2[8], a3[8];
#pragma unroll
    for (int e = 0; e < 8; e++) a1[e] = __shfl_xor(acc[e], 1);
    if (F8 == 4) {
#pragma unroll
        for (int e = 0; e < 8; e++) a2[e] = __shfl_xor(acc[e], 2);
#pragma unroll
        for (int e = 0; e < 8; e++) a3[e] = __shfl_xor(a1[e], 2);
    }

    // ---- per-lane matmul: outputs [f8*NOUT4*4 .. +NOUT4*4) ----
    int fo0 = f8 * NOUT4;
    float4 o4[NOUT4];
#pragma unroll
    for (int j = 0; j < NOUT4; j++) o4[j] = make_float4(0.f, 0.f, 0.f, 0.f);

#define MM_CHUNK(AR, C)                                               \
    {                                                                 \
        int c_ = (C);                                                 \
        _Pragma("unroll") for (int e = 0; e < 8; e++) {               \
            int fi = c_ * 8 + e;                                      \
            float r = (AR)[e];                                        \
            _Pragma("unroll") for (int j = 0; j < NOUT4; j++) {       \
                float4 wv = Ws4[fi * 8 + fo0 + j];                    \
                o4[j].x += r * wv.x;                                  \
                o4[j].y += r * wv.y;                                  \
                o4[j].z += r * wv.z;                                  \
                o4[j].w += r * wv.w;                                  \
            }                                                         \
        }                                                             \
    }

    MM_CHUNK(acc, f8)
    MM_CHUNK(a1, f8 ^ 1)
    if (F8 == 4) {
        MM_CHUNK(a2, f8 ^ 2)
        MM_CHUNK(a3, f8 ^ 3)
    }
#undef MM_CHUNK

    // ---- epilogue ----
    float di = dinv[n];
    float4 v4[NOUT4];
#pragma unroll
    for (int j = 0; j < NOUT4; j++) {
        float4 bb = bs4[fo0 + j];
        float4 v;
        v.x = o4[j].x * di + bb.x;
        v.y = o4[j].y * di + bb.y;
        v.z = o4[j].z * di + bb.z;
        v.w = o4[j].w * di + bb.w;
        v.x = v.x > 0.f ? v.x : 0.f;
        v.y = v.y > 0.f ? v.y : 0.f;
        v.z = v.z > 0.f ? v.z : 0.f;
        v.w = v.w > 0.f ? v.w : 0.f;
        v4[j] = v;
    }
    if (LAST) {
        float4* o = (float4*)outp;
#pragma unroll
        for (int j = 0; j < NOUT4; j++) o[(size_t)n * 8 + fo0 + j] = v4[j];
    } else {
        half8* o = (half8*)outp;
#pragma unroll
        for (int pr = 0; pr < NOUT4 / 2; pr++) {
            float4 lo = v4[2 * pr], hi = v4[2 * pr + 1];
            half8 hh;
            hh[0] = (_Float16)(lo.x * di); hh[1] = (_Float16)(lo.y * di);
            hh[2] = (_Float16)(lo.z * di); hh[3] = (_Float16)(lo.w * di);
            hh[4] = (_Float16)(hi.x * di); hh[5] = (_Float16)(hi.y * di);
            hh[6] = (_Float16)(hi.z * di); hh[7] = (_Float16)(hi.w * di);
            o[(size_t)n * 4 + fo0 / 2 + pr] = hh;
        }
    }
}

// ---- fc1 partials: 4-deep dual banks, VGPR-capped for 4 waves/SIMD ----
// part[b][g][j] = sum_{k in chunk b} h3[g][k]*w[k][j]; w/h3 nt (stream-once);
// part stored normally (read right back by reduce -> let L3 keep it).
__global__ __launch_bounds__(256, 4) void fc1_kernel(const float* __restrict__ h3,
                                                     const float* __restrict__ w,
                                                     float* __restrict__ part) {
    __shared__ float hs[NUM_GRAPHS * FC1_KCHUNK];  // 8 KB
    int t = threadIdx.x;
    int kbase = blockIdx.x * FC1_KCHUNK;
    for (int i = t; i < NUM_GRAPHS * FC1_KCHUNK; i += 256) {
        int g = i >> 7;  // FC1_KCHUNK == 128
        int kk = i & 127;
        hs[i] = ntloadf(h3 + (size_t)g * FC1_IN + kbase + kk);
    }
    __syncthreads();
    int kl = t & 3;
    int c = t >> 2;  // 0..63: float4 column
    const float4* w4 = (const float4*)w;  // row k = 64 float4
    float4 acc[NUM_GRAPHS];
#pragma unroll
    for (int g = 0; g < NUM_GRAPHS; g++) acc[g] = make_float4(0.f, 0.f, 0.f, 0.f);

    // thread owns rows k = kbase + kl + 4*i, i = 0..31; 4-deep dual banks
    float4 wa[4], wb[4];
#define LOADW(BUF, I0)                                                        \
    _Pragma("unroll") for (int u = 0; u < 4; u++)                             \
        (BUF)[u] = ntload4(&w4[(size_t)(kbase + kl + 4 * ((I0) + u)) * (FC1_OUT / 4) + c]);
#define COMPW(BUF, I0)                                                        \
    _Pragma("unroll") for (int u = 0; u < 4; u++) {                           \
        int kk = kl + 4 * ((I0) + u);                                         \
        _Pragma("unroll") for (int g = 0; g < NUM_GRAPHS; g++) {              \
            float hg = hs[g * FC1_KCHUNK + kk];                               \
            acc[g].x += hg * (BUF)[u].x;                                      \
            acc[g].y += hg * (BUF)[u].y;                                      \
            acc[g].z += hg * (BUF)[u].z;                                      \
            acc[g].w += hg * (BUF)[u].w;                                      \
        }                                                                     \
    }

    LOADW(wa, 0)
    LOADW(wb, 4)
    COMPW(wa, 0)
    LOADW(wa, 8)
    COMPW(wb, 4)
    LOADW(wb, 12)
    COMPW(wa, 8)
    LOADW(wa, 16)
    COMPW(wb, 12)
    LOADW(wb, 20)
    COMPW(wa, 16)
    LOADW(wa, 24)
    COMPW(wb, 20)
    LOADW(wb, 28)
    COMPW(wa, 24)
    COMPW(wb, 28)
#undef LOADW
#undef COMPW

#pragma unroll
    for (int g = 0; g < NUM_GRAPHS; g++) {
        acc[g].x += __shfl_xor(acc[g].x, 1);
        acc[g].y += __shfl_xor(acc[g].y, 1);
        acc[g].z += __shfl_xor(acc[g].z, 1);
        acc[g].w += __shfl_xor(acc[g].w, 1);
        acc[g].x += __shfl_xor(acc[g].x, 2);
        acc[g].y += __shfl_xor(acc[g].y, 2);
        acc[g].z += __shfl_xor(acc[g].z, 2);
        acc[g].w += __shfl_xor(acc[g].w, 2);
    }
    if (kl == 0) {
        float4* p4 = (float4*)part;
#pragma unroll
        for (int g = 0; g < NUM_GRAPHS; g++)
            p4[(size_t)blockIdx.x * (NUM_GRAPHS * FC1_OUT / 4) + g * (FC1_OUT / 4) + c] = acc[g];
    }
}

// ---- reduce partials -> partial16[bq][j']; 256 blocks; plain (cached) loads ----
__global__ void reduce_kernel(const float* __restrict__ part, float* __restrict__ partial16) {
    int tid = blockIdx.x * 256 + threadIdx.x;  // 65536 threads
    int j = tid & 4095;
    int bq = tid >> 12;  // 0..15
    float s = 0.f;
#pragma unroll 8
    for (int u = 0; u < FC1_BLOCKS / RED_Q; u++)
        s += part[(size_t)(bq * (FC1_BLOCKS / RED_Q) + u) * (NUM_GRAPHS * FC1_OUT) + j];
    partial16[bq * (NUM_GRAPHS * FC1_OUT) + j] = s;
}

// ---- fc2: folds the 16 partials, bias+relu, then 256->64 matmul ----
__global__ void fc2_kernel(const float* __restrict__ partial16, const float* __restrict__ fc1_b,
                           const float* __restrict__ w2, const float* __restrict__ b2,
                           float* __restrict__ out) {
    int g = blockIdx.x;
    int j = threadIdx.x;  // 0..63
    __shared__ float vs[FC1_OUT];
    for (int k = j; k < FC1_OUT; k += 64) {
        float s = fc1_b[k];
#pragma unroll
        for (int bq = 0; bq < RED_Q; bq++)
            s += partial16[bq * (NUM_GRAPHS * FC1_OUT) + g * FC1_OUT + k];
        vs[k] = s > 0.f ? s : 0.f;
    }
    __syncthreads();
    float acc = b2[j];
    for (int k = 0; k < FC1_OUT; k++) acc += vs[k] * w2[k * FC2_OUT + j];
    out[g * FC2_OUT + j] = acc;
}

extern "C" void kernel_launch(void* const* d_in, const int* in_sizes, int n_in,
                              void* d_out, int out_size, void* d_ws, size_t ws_size,
                              hipStream_t stream) {
    const float* x = (const float*)d_in[0];
    const int* ei = (const int*)d_in[1];
    const int* src = ei;
    const int* dst = ei + NUM_EDGES;
    const float* W1 = (const float*)d_in[2];
    const float* b1 = (const float*)d_in[3];
    const float* W2 = (const float*)d_in[4];
    const float* b2 = (const float*)d_in[5];
    const float* W3 = (const float*)d_in[6];
    const float* b3 = (const float*)d_in[7];
    const float* fc1_w = (const float*)d_in[8];
    const float* fc1_b = (const float*)d_in[9];
    const float* fc2_w = (const float*)d_in[10];
    const float* fc2_b = (const float*)d_in[11];
    float* out = (float*)d_out;

    // workspace layout (re-poisoned 0xAA each call)
    int* bucket_cursor = (int*)d_ws;                       // 1 KB
    int* binned = bucket_cursor + 256;                     // 5.24 MB
    unsigned short* csr = (unsigned short*)(binned + NB * BUCKET_CAP);  // 4.19 MB
    int* rowstart = (int*)(csr + NB * CSR_CAP);            // 256 KB
    int* rowend = rowstart + N_NODES;                      // 256 KB
    float* dinv = (float*)(rowend + N_NODES);              // 256 KB
    half8* p0 = (half8*)(dinv + N_NODES);                  // N*16 fp16 = 2 MB
    half8* pA = (half8*)(p0 + (size_t)N_NODES * 2);        // N*32 fp16 = 4 MB
    half8* pB = (half8*)(pA + (size_t)N_NODES * 4);        // N*32 fp16 = 4 MB
    float* h3 = (float*)(pB + (size_t)N_NODES * 4);        // N*32 f32 = 8 MB
    float* part = h3 + (size_t)N_NODES * HIDDEN;           // 16 MB
    float* partial16 = part + (size_t)FC1_BLOCKS * NUM_GRAPHS * FC1_OUT;  // 256 KB

    initcur_kernel<<<1, 256, 0, stream>>>(bucket_cursor);
    binA_kernel<<<NUM_EDGES / EPB_A, 256, 0, stream>>>(src, dst, bucket_cursor, binned);
    sortB_kernel<<<NB, 1024, 0, stream>>>(bucket_cursor, binned, csr, rowstart, rowend, dinv, x, p0);

    // layer 1: fused gather(16-feat p0) + matmul W1 -> pA (fp16)
    gmm_kernel<IN_FEAT, false><<<N_NODES * 2 / 256, 256, 0, stream>>>(
        rowstart, rowend, csr, p0, W1, b1, dinv, pA);
    // layer 2: fused gather(32-feat pA) + matmul W2 -> pB (fp16)
    gmm_kernel<HIDDEN, false><<<N_NODES * 4 / 256, 256, 0, stream>>>(
        rowstart, rowend, csr, pA, W2, b2, dinv, pB);
    // layer 3: fused gather(32-feat pB) + matmul W3 -> h3 (fp32)
    gmm_kernel<HIDDEN, true><<<N_NODES * 4 / 256, 256, 0, stream>>>(
        rowstart, rowend, csr, pB, W3, b3, dinv, h3);

    fc1_kernel<<<FC1_BLOCKS, 256, 0, stream>>>(h3, fc1_w, part);
    reduce_kernel<<<256, 256, 0, stream>>>(part, partial16);
    fc2_kernel<<<NUM_GRAPHS, 64, 0, stream>>>(partial16, fc1_b, fc2_w, fc2_b, out);
}

// Round 11
// 300.202 us; speedup vs baseline: 2.5545x; 1.0331x over previous
//
#include <hip/hip_runtime.h>

#define N_NODES 65536
#define IN_FEAT 16
#define HIDDEN 32
#define NUM_EDGES 1048576
#define NUM_GRAPHS 16
#define NODES_PER_GRAPH 4096
#define FC1_IN (NODES_PER_GRAPH * HIDDEN) /* 131072 */
#define FC1_OUT 256
#define FC2_OUT 64
#define FC1_KCHUNK 128
#define FC1_BLOCKS (FC1_IN / FC1_KCHUNK) /* 1024 */
#define RED_Q 16        /* reduce fan-in groups */
#define NB 256          /* buckets = dst>>8 */
#define BUCKET_CAP 5120 /* binned: mean 4096, sd 64 -> 16 sigma headroom */
#define CSR_CAP 8192    /* csr: 4096 + row-align pad + headroom */
#define EPB_A 4096      /* edges per phase-A block */

typedef _Float16 half8 __attribute__((ext_vector_type(8)));         // 16 B
typedef float floatx4 __attribute__((ext_vector_type(4)));          // native vec for nt builtins
typedef unsigned short ushort8 __attribute__((ext_vector_type(8))); // 16 B

__device__ __forceinline__ float4 ntload4(const float4* p) {
    floatx4 v = __builtin_nontemporal_load((const floatx4*)p);
    return make_float4(v.x, v.y, v.z, v.w);
}
__device__ __forceinline__ void ntstore4(float4* p, float4 v) {
    floatx4 w = {v.x, v.y, v.z, v.w};
    __builtin_nontemporal_store(w, (floatx4*)p);
}
__device__ __forceinline__ int ntloadi(const int* p) {
    return __builtin_nontemporal_load(p);
}
__device__ __forceinline__ float ntloadf(const float* p) {
    return __builtin_nontemporal_load(p);
}

// ---- init bucket cursors to fixed-capacity bases ----
__global__ void initcur_kernel(int* __restrict__ bucket_cursor) {
    bucket_cursor[threadIdx.x] = threadIdx.x * BUCKET_CAP;
}

// ---- phase A: bin edges by dst>>8 with chunk-contiguous writes ----
// src/dst are stream-once: non-temporal (don't evict L3 lines for them).
__global__ void binA_kernel(const int* __restrict__ src, const int* __restrict__ dst,
                            int* __restrict__ bucket_cursor, int* __restrict__ binned) {
    __shared__ int hist[NB];
    __shared__ int base[NB];
    __shared__ int cur[NB];
    int t = threadIdx.x;
    hist[t] = 0;
    __syncthreads();
    int e0 = blockIdx.x * EPB_A;
    int s[16], d[16];
#pragma unroll
    for (int i = 0; i < 16; i++) {
        int e = e0 + t + 256 * i;
        s[i] = ntloadi(src + e);
        d[i] = ntloadi(dst + e);
    }
#pragma unroll
    for (int i = 0; i < 16; i++) atomicAdd(&hist[d[i] >> 8], 1);
    __syncthreads();
    base[t] = atomicAdd(&bucket_cursor[t], hist[t]);
    cur[t] = 0;
    __syncthreads();
#pragma unroll
    for (int i = 0; i < 16; i++) {
        int b = d[i] >> 8;
        int r = atomicAdd(&cur[b], 1);
        binned[base[b] + r] = s[i] | ((d[i] & 255) << 16);
    }
}

// ---- phase B: per-bucket LDS counting sort by dst low byte (512 threads) ----
// emits csr (ushort, 16B-aligned row starts), rowstart/rowend, dinv, p0 = x*dinv fp16.
__global__ void sortB_kernel(const int* __restrict__ bucket_cursor, const int* __restrict__ binned,
                             unsigned short* __restrict__ csr, int* __restrict__ rowstart,
                             int* __restrict__ rowend, float* __restrict__ dinv,
                             const float* __restrict__ x, half8* __restrict__ p0) {
    __shared__ int hist[NB];
    __shared__ int scanbuf[NB];
    __shared__ int start[NB];
    __shared__ int cur[NB];
    int t = threadIdx.x;  // 0..511
    int b = blockIdx.x;
    int bbase = b * BUCKET_CAP;
    int cbase = b * CSR_CAP;
    int cnt = bucket_cursor[b] - bbase;
    if (t < NB) hist[t] = 0;
    __syncthreads();
    for (int i = t; i < cnt; i += 512) atomicAdd(&hist[binned[bbase + i] >> 16], 1);
    __syncthreads();
    int v = 0;
    if (t < NB) {
        v = hist[t];
        scanbuf[t] = (v + 7) & ~7;  // padded row size -> 16B-aligned starts
    }
    __syncthreads();
    for (int off = 1; off < NB; off <<= 1) {
        int y = 0;
        if (t < NB && t >= off) y = scanbuf[t - off];
        __syncthreads();
        if (t < NB) scanbuf[t] += y;
        __syncthreads();
    }
    if (t < NB) {
        start[t] = scanbuf[t] - ((v + 7) & ~7);  // exclusive prefix of padded sizes
        cur[t] = 0;
    }
    __syncthreads();
    for (int i = t; i < cnt; i += 512) {
        int p = binned[bbase + i];
        int dl = p >> 16;
        int r = atomicAdd(&cur[dl], 1);
        csr[cbase + start[dl] + r] = (unsigned short)(p & 0xFFFF);
    }
    if (t < NB) {
        int n = b * NB + t;
        int excl = start[t];
        rowstart[n] = cbase + excl;
        rowend[n] = cbase + excl + v;
        dinv[n] = rsqrtf((float)v + 1.0f);
    }
    // p0 prescale: 512 threads = 256 nodes x 2 half8-chunks
    {
        int nl = t >> 1;
        int qq = t & 1;
        int n = b * NB + nl;
        float di = rsqrtf((float)hist[nl] + 1.0f);
        const float4* x4 = (const float4*)x;
        float4 a = x4[(size_t)n * 4 + 2 * qq];
        float4 c = x4[(size_t)n * 4 + 2 * qq + 1];
        half8 hh;
        hh[0] = (_Float16)(a.x * di); hh[1] = (_Float16)(a.y * di);
        hh[2] = (_Float16)(a.z * di); hh[3] = (_Float16)(a.w * di);
        hh[4] = (_Float16)(c.x * di); hh[5] = (_Float16)(c.y * di);
        hh[6] = (_Float16)(c.z * di); hh[7] = (_Float16)(c.w * di);
        p0[(size_t)n * 2 + qq] = hh;
    }
}

// ---- fused gather+matmul, quad-grain (no mid-kernel block barrier) ----
// CSR rows start 16B-aligned, so the 8-wide loop loads one ushort8 per iter.
template <int FIN, bool LAST>
__global__ void gmm_kernel(const int* __restrict__ rowstart, const int* __restrict__ rowend,
                           const unsigned short* __restrict__ csr, const half8* __restrict__ p,
                           const float* __restrict__ W, const float* __restrict__ bias,
                           const float* __restrict__ dinv, void* __restrict__ outp) {
    constexpr int F8 = FIN / 8;        // half8 chunks per input row: 2 or 4
    constexpr int LOG2F8 = (FIN == 16) ? 1 : 2;
    constexpr int NOUT4 = 8 / F8;      // float4 output groups per lane: 4 or 2
    __shared__ float4 Ws4[FIN * 8];    // W[FIN][32] as float4
    __shared__ float4 bs4[8];
    int t = threadIdx.x;
    for (int i = t; i < FIN * 8; i += 256) Ws4[i] = ((const float4*)W)[i];
    if (t < 8) bs4[t] = ((const float4*)bias)[t];
    __syncthreads();  // only barrier: before divergent work, no straggler cost

    int f8 = t & (F8 - 1);
    int n = (blockIdx.x * 256 + t) >> LOG2F8;

    // ---- gather stage ----
    half8 self = p[(size_t)n * F8 + f8];
    float acc[8];
#pragma unroll
    for (int e = 0; e < 8; e++) acc[e] = (float)self[e];
    int beg = rowstart[n];  // 16B-aligned (multiple of 8)
    int end = rowend[n];
    int i = beg;
    for (; i + 8 <= end; i += 8) {
        ushort8 sv = *(const ushort8*)(csr + i);  // single dwordx4 load
        half8 a[8];
#pragma unroll
        for (int u = 0; u < 8; u++) a[u] = p[(size_t)sv[u] * F8 + f8];
#pragma unroll
        for (int u = 0; u < 8; u++)
#pragma unroll
            for (int e = 0; e < 8; e++) acc[e] += (float)a[u][e];
    }
    if (i + 4 <= end) {
        int s[4];
#pragma unroll
        for (int u = 0; u < 4; u++) s[u] = csr[i + u];
        half8 a[4];
#pragma unroll
        for (int u = 0; u < 4; u++) a[u] = p[(size_t)s[u] * F8 + f8];
#pragma unroll
        for (int u = 0; u < 4; u++)
#pragma unroll
            for (int e = 0; e < 8; e++) acc[e] += (float)a[u][e];
        i += 4;
    }
    for (; i < end; i++) {
        half8 a = p[(size_t)csr[i] * F8 + f8];
#pragma unroll
        for (int e = 0; e < 8; e++) acc[e] += (float)a[e];
    }

    // ---- in-quad butterfly: lane gains all FIN q-features ----
    float a1[8], a2[8], a3[8];
#pragma unroll
    for (int e = 0; e < 8; e++) a1[e] = __shfl_xor(acc[e], 1);
    if (F8 == 4) {
#pragma unroll
        for (int e = 0; e < 8; e++) a2[e] = __shfl_xor(acc[e], 2);
#pragma unroll
        for (int e = 0; e < 8; e++) a3[e] = __shfl_xor(a1[e], 2);
    }

    // ---- per-lane matmul: outputs [f8*NOUT4*4 .. +NOUT4*4) ----
    int fo0 = f8 * NOUT4;
    float4 o4[NOUT4];
#pragma unroll
    for (int j = 0; j < NOUT4; j++) o4[j] = make_float4(0.f, 0.f, 0.f, 0.f);

#define MM_CHUNK(AR, C)                                               \
    {                                                                 \
        int c_ = (C);                                                 \
        _Pragma("unroll") for (int e = 0; e < 8; e++) {               \
            int fi = c_ * 8 + e;                                      \
            float r = (AR)[e];                                        \
            _Pragma("unroll") for (int j = 0; j < NOUT4; j++) {       \
                float4 wv = Ws4[fi * 8 + fo0 + j];                    \
                o4[j].x += r * wv.x;                                  \
                o4[j].y += r * wv.y;                                  \
                o4[j].z += r * wv.z;                                  \
                o4[j].w += r * wv.w;                                  \
            }                                                         \
        }                                                             \
    }

    MM_CHUNK(acc, f8)
    MM_CHUNK(a1, f8 ^ 1)
    if (F8 == 4) {
        MM_CHUNK(a2, f8 ^ 2)
        MM_CHUNK(a3, f8 ^ 3)
    }
#undef MM_CHUNK

    // ---- epilogue ----
    float di = dinv[n];
    float4 v4[NOUT4];
#pragma unroll
    for (int j = 0; j < NOUT4; j++) {
        float4 bb = bs4[fo0 + j];
        float4 v;
        v.x = o4[j].x * di + bb.x;
        v.y = o4[j].y * di + bb.y;
        v.z = o4[j].z * di + bb.z;
        v.w = o4[j].w * di + bb.w;
        v.x = v.x > 0.f ? v.x : 0.f;
        v.y = v.y > 0.f ? v.y : 0.f;
        v.z = v.z > 0.f ? v.z : 0.f;
        v.w = v.w > 0.f ? v.w : 0.f;
        v4[j] = v;
    }
    if (LAST) {
        float4* o = (float4*)outp;
#pragma unroll
        for (int j = 0; j < NOUT4; j++) o[(size_t)n * 8 + fo0 + j] = v4[j];
    } else {
        half8* o = (half8*)outp;
#pragma unroll
        for (int pr = 0; pr < NOUT4 / 2; pr++) {
            float4 lo = v4[2 * pr], hi = v4[2 * pr + 1];
            half8 hh;
            hh[0] = (_Float16)(lo.x * di); hh[1] = (_Float16)(lo.y * di);
            hh[2] = (_Float16)(lo.z * di); hh[3] = (_Float16)(lo.w * di);
            hh[4] = (_Float16)(hi.x * di); hh[5] = (_Float16)(hi.y * di);
            hh[6] = (_Float16)(hi.z * di); hh[7] = (_Float16)(hi.w * di);
            o[(size_t)n * 4 + fo0 / 2 + pr] = hh;
        }
    }
}

// ---- fc1 partials; 4-deep dual banks (32 VGPR), NO launch-bounds cap ----
// part[b][g][j] = sum_{k in chunk b} h3[g][k]*w[k][j]; w/h3 nt (stream-once);
// part nt-stored (stream-once to reduce).
__global__ __launch_bounds__(256) void fc1_kernel(const float* __restrict__ h3,
                                                  const float* __restrict__ w,
                                                  float* __restrict__ part) {
    __shared__ float hs[NUM_GRAPHS * FC1_KCHUNK];  // 8 KB
    int t = threadIdx.x;
    int kbase = blockIdx.x * FC1_KCHUNK;
    for (int i = t; i < NUM_GRAPHS * FC1_KCHUNK; i += 256) {
        int g = i >> 7;  // FC1_KCHUNK == 128
        int kk = i & 127;
        hs[i] = ntloadf(h3 + (size_t)g * FC1_IN + kbase + kk);
    }
    __syncthreads();
    int kl = t & 3;
    int c = t >> 2;  // 0..63: float4 column
    const float4* w4 = (const float4*)w;  // row k = 64 float4
    float4 acc[NUM_GRAPHS];
#pragma unroll
    for (int g = 0; g < NUM_GRAPHS; g++) acc[g] = make_float4(0.f, 0.f, 0.f, 0.f);

    // thread owns rows k = kbase + kl + 4*i, i = 0..31; 4-deep dual banks (32 VGPR)
    float4 wa[4], wb[4];
#define LOADW(BUF, I0)                                                        \
    _Pragma("unroll") for (int u = 0; u < 4; u++)                             \
        (BUF)[u] = ntload4(&w4[(size_t)(kbase + kl + 4 * ((I0) + u)) * (FC1_OUT / 4) + c]);
#define COMPW(BUF, I0)                                                        \
    _Pragma("unroll") for (int u = 0; u < 4; u++) {                           \
        int kk = kl + 4 * ((I0) + u);                                         \
        _Pragma("unroll") for (int g = 0; g < NUM_GRAPHS; g++) {              \
            float hg = hs[g * FC1_KCHUNK + kk];                               \
            acc[g].x += hg * (BUF)[u].x;                                      \
            acc[g].y += hg * (BUF)[u].y;                                      \
            acc[g].z += hg * (BUF)[u].z;                                      \
            acc[g].w += hg * (BUF)[u].w;                                      \
        }                                                                     \
    }

    LOADW(wa, 0)
    LOADW(wb, 4)
    COMPW(wa, 0)
    LOADW(wa, 8)
    COMPW(wb, 4)
    LOADW(wb, 12)
    COMPW(wa, 8)
    LOADW(wa, 16)
    COMPW(wb, 12)
    LOADW(wb, 20)
    COMPW(wa, 16)
    LOADW(wa, 24)
    COMPW(wb, 20)
    LOADW(wb, 28)
    COMPW(wa, 24)
    COMPW(wb, 28)
#undef LOADW
#undef COMPW

#pragma unroll
    for (int g = 0; g < NUM_GRAPHS; g++) {
        acc[g].x += __shfl_xor(acc[g].x, 1);
        acc[g].y += __shfl_xor(acc[g].y, 1);
        acc[g].z += __shfl_xor(acc[g].z, 1);
        acc[g].w += __shfl_xor(acc[g].w, 1);
        acc[g].x += __shfl_xor(acc[g].x, 2);
        acc[g].y += __shfl_xor(acc[g].y, 2);
        acc[g].z += __shfl_xor(acc[g].z, 2);
        acc[g].w += __shfl_xor(acc[g].w, 2);
    }
    if (kl == 0) {
        float4* p4 = (float4*)part;
#pragma unroll
        for (int g = 0; g < NUM_GRAPHS; g++)
            ntstore4(&p4[(size_t)blockIdx.x * (NUM_GRAPHS * FC1_OUT / 4) + g * (FC1_OUT / 4) + c],
                     acc[g]);
    }
}

// ---- reduce partials -> partial16[bq][j']; 256 blocks (full GPU); nt reads ----
__global__ void reduce_kernel(const float* __restrict__ part, float* __restrict__ partial16) {
    int tid = blockIdx.x * 256 + threadIdx.x;  // 65536 threads
    int j = tid & 4095;
    int bq = tid >> 12;  // 0..15
    float s = 0.f;
#pragma unroll 8
    for (int u = 0; u < FC1_BLOCKS / RED_Q; u++)
        s += ntloadf(&part[(size_t)(bq * (FC1_BLOCKS / RED_Q) + u) * (NUM_GRAPHS * FC1_OUT) + j]);
    partial16[bq * (NUM_GRAPHS * FC1_OUT) + j] = s;
}

// ---- fc2: folds the 16 partials, bias+relu, then 256->64 matmul ----
__global__ void fc2_kernel(const float* __restrict__ partial16, const float* __restrict__ fc1_b,
                           const float* __restrict__ w2, const float* __restrict__ b2,
                           float* __restrict__ out) {
    int g = blockIdx.x;
    int j = threadIdx.x;  // 0..63
    __shared__ float vs[FC1_OUT];
    for (int k = j; k < FC1_OUT; k += 64) {
        float s = fc1_b[k];
#pragma unroll
        for (int bq = 0; bq < RED_Q; bq++)
            s += partial16[bq * (NUM_GRAPHS * FC1_OUT) + g * FC1_OUT + k];
        vs[k] = s > 0.f ? s : 0.f;
    }
    __syncthreads();
    float acc = b2[j];
    for (int k = 0; k < FC1_OUT; k++) acc += vs[k] * w2[k * FC2_OUT + j];
    out[g * FC2_OUT + j] = acc;
}

extern "C" void kernel_launch(void* const* d_in, const int* in_sizes, int n_in,
                              void* d_out, int out_size, void* d_ws, size_t ws_size,
                              hipStream_t stream) {
    const float* x = (const float*)d_in[0];
    const int* ei = (const int*)d_in[1];
    const int* src = ei;
    const int* dst = ei + NUM_EDGES;
    const float* W1 = (const float*)d_in[2];
    const float* b1 = (const float*)d_in[3];
    const float* W2 = (const float*)d_in[4];
    const float* b2 = (const float*)d_in[5];
    const float* W3 = (const float*)d_in[6];
    const float* b3 = (const float*)d_in[7];
    const float* fc1_w = (const float*)d_in[8];
    const float* fc1_b = (const float*)d_in[9];
    const float* fc2_w = (const float*)d_in[10];
    const float* fc2_b = (const float*)d_in[11];
    float* out = (float*)d_out;

    // workspace layout (re-poisoned 0xAA each call)
    int* bucket_cursor = (int*)d_ws;                       // 1 KB
    int* binned = bucket_cursor + 256;                     // 5.24 MB
    unsigned short* csr = (unsigned short*)(binned + NB * BUCKET_CAP);  // 4.19 MB
    int* rowstart = (int*)(csr + NB * CSR_CAP);            // 256 KB
    int* rowend = rowstart + N_NODES;                      // 256 KB
    float* dinv = (float*)(rowend + N_NODES);              // 256 KB
    half8* p0 = (half8*)(dinv + N_NODES);                  // N*16 fp16 = 2 MB
    half8* pA = (half8*)(p0 + (size_t)N_NODES * 2);        // N*32 fp16 = 4 MB
    half8* pB = (half8*)(pA + (size_t)N_NODES * 4);        // N*32 fp16 = 4 MB
    float* h3 = (float*)(pB + (size_t)N_NODES * 4);        // N*32 f32 = 8 MB
    float* part = h3 + (size_t)N_NODES * HIDDEN;           // 16 MB
    float* partial16 = part + (size_t)FC1_BLOCKS * NUM_GRAPHS * FC1_OUT;  // 256 KB

    initcur_kernel<<<1, 256, 0, stream>>>(bucket_cursor);
    binA_kernel<<<NUM_EDGES / EPB_A, 256, 0, stream>>>(src, dst, bucket_cursor, binned);
    sortB_kernel<<<NB, 512, 0, stream>>>(bucket_cursor, binned, csr, rowstart, rowend, dinv, x, p0);

    // layer 1: fused gather(16-feat p0) + matmul W1 -> pA (fp16)
    gmm_kernel<IN_FEAT, false><<<N_NODES * 2 / 256, 256, 0, stream>>>(
        rowstart, rowend, csr, p0, W1, b1, dinv, pA);
    // layer 2: fused gather(32-feat pA) + matmul W2 -> pB (fp16)
    gmm_kernel<HIDDEN, false><<<N_NODES * 4 / 256, 256, 0, stream>>>(
        rowstart, rowend, csr, pA, W2, b2, dinv, pB);
    // layer 3: fused gather(32-feat pB) + matmul W3 -> h3 (fp32)
    gmm_kernel<HIDDEN, true><<<N_NODES * 4 / 256, 256, 0, stream>>>(
        rowstart, rowend, csr, pB, W3, b3, dinv, h3);

    fc1_kernel<<<FC1_BLOCKS, 256, 0, stream>>>(h3, fc1_w, part);
    reduce_kernel<<<256, 256, 0, stream>>>(part, partial16);
    fc2_kernel<<<NUM_GRAPHS, 64, 0, stream>>>(partial16, fc1_b, fc2_w, fc2_b, out);
}

// Round 12
// 291.997 us; speedup vs baseline: 2.6262x; 1.0281x over previous
//
#include <hip/hip_runtime.h>

#define N_NODES 65536
#define IN_FEAT 16
#define HIDDEN 32
#define NUM_EDGES 1048576
#define NUM_GRAPHS 16
#define NODES_PER_GRAPH 4096
#define FC1_IN (NODES_PER_GRAPH * HIDDEN) /* 131072 */
#define FC1_OUT 256
#define FC2_OUT 64
#define FC1_KCHUNK 128
#define FC1_BLOCKS (FC1_IN / FC1_KCHUNK) /* 1024 */
#define RED_Q 16        /* reduce fan-in groups */
#define NB 256          /* buckets = dst>>8 */
#define BUCKET_CAP 5120 /* binned: mean 4096, sd 64 -> 16 sigma headroom */
#define CSR_CAP 8192    /* csr: 4096 + row-align pad + headroom */
#define EPB_A 4096      /* edges per phase-A block */

typedef _Float16 half8 __attribute__((ext_vector_type(8)));         // 16 B
typedef float floatx4 __attribute__((ext_vector_type(4)));          // native vec for nt builtins
typedef unsigned short ushort8 __attribute__((ext_vector_type(8))); // 16 B

__device__ __forceinline__ float4 ntload4(const float4* p) {
    floatx4 v = __builtin_nontemporal_load((const floatx4*)p);
    return make_float4(v.x, v.y, v.z, v.w);
}
__device__ __forceinline__ int ntloadi(const int* p) {
    return __builtin_nontemporal_load(p);
}
__device__ __forceinline__ float ntloadf(const float* p) {
    return __builtin_nontemporal_load(p);
}

// ---- init bucket cursors to fixed-capacity bases ----
__global__ void initcur_kernel(int* __restrict__ bucket_cursor) {
    bucket_cursor[threadIdx.x] = threadIdx.x * BUCKET_CAP;
}

// ---- phase A: bin edges by dst>>8 with chunk-contiguous writes ----
// src/dst are stream-once: non-temporal (don't evict L3 lines for them).
__global__ void binA_kernel(const int* __restrict__ src, const int* __restrict__ dst,
                            int* __restrict__ bucket_cursor, int* __restrict__ binned) {
    __shared__ int hist[NB];
    __shared__ int base[NB];
    __shared__ int cur[NB];
    int t = threadIdx.x;
    hist[t] = 0;
    __syncthreads();
    int e0 = blockIdx.x * EPB_A;
    int s[16], d[16];
#pragma unroll
    for (int i = 0; i < 16; i++) {
        int e = e0 + t + 256 * i;
        s[i] = ntloadi(src + e);
        d[i] = ntloadi(dst + e);
    }
#pragma unroll
    for (int i = 0; i < 16; i++) atomicAdd(&hist[d[i] >> 8], 1);
    __syncthreads();
    base[t] = atomicAdd(&bucket_cursor[t], hist[t]);
    cur[t] = 0;
    __syncthreads();
#pragma unroll
    for (int i = 0; i < 16; i++) {
        int b = d[i] >> 8;
        int r = atomicAdd(&cur[b], 1);
        binned[base[b] + r] = s[i] | ((d[i] & 255) << 16);
    }
}

// ---- phase B: per-bucket LDS counting sort by dst low byte (512 threads) ----
// emits csr (ushort, 16B-aligned row starts), rowstart/rowend, dinv, p0 = x*dinv fp16.
__global__ void sortB_kernel(const int* __restrict__ bucket_cursor, const int* __restrict__ binned,
                             unsigned short* __restrict__ csr, int* __restrict__ rowstart,
                             int* __restrict__ rowend, float* __restrict__ dinv,
                             const float* __restrict__ x, half8* __restrict__ p0) {
    __shared__ int hist[NB];
    __shared__ int scanbuf[NB];
    __shared__ int start[NB];
    __shared__ int cur[NB];
    int t = threadIdx.x;  // 0..511
    int b = blockIdx.x;
    int bbase = b * BUCKET_CAP;
    int cbase = b * CSR_CAP;
    int cnt = bucket_cursor[b] - bbase;
    if (t < NB) hist[t] = 0;
    __syncthreads();
    for (int i = t; i < cnt; i += 512) atomicAdd(&hist[binned[bbase + i] >> 16], 1);
    __syncthreads();
    int v = 0;
    if (t < NB) {
        v = hist[t];
        scanbuf[t] = (v + 7) & ~7;  // padded row size -> 16B-aligned starts
    }
    __syncthreads();
    for (int off = 1; off < NB; off <<= 1) {
        int y = 0;
        if (t < NB && t >= off) y = scanbuf[t - off];
        __syncthreads();
        if (t < NB) scanbuf[t] += y;
        __syncthreads();
    }
    if (t < NB) {
        start[t] = scanbuf[t] - ((v + 7) & ~7);  // exclusive prefix of padded sizes
        cur[t] = 0;
    }
    __syncthreads();
    for (int i = t; i < cnt; i += 512) {
        int p = binned[bbase + i];
        int dl = p >> 16;
        int r = atomicAdd(&cur[dl], 1);
        csr[cbase + start[dl] + r] = (unsigned short)(p & 0xFFFF);
    }
    if (t < NB) {
        int n = b * NB + t;
        int excl = start[t];
        rowstart[n] = cbase + excl;
        rowend[n] = cbase + excl + v;
        dinv[n] = rsqrtf((float)v + 1.0f);
    }
    // p0 prescale: 512 threads = 256 nodes x 2 half8-chunks
    {
        int nl = t >> 1;
        int qq = t & 1;
        int n = b * NB + nl;
        float di = rsqrtf((float)hist[nl] + 1.0f);
        const float4* x4 = (const float4*)x;
        float4 a = x4[(size_t)n * 4 + 2 * qq];
        float4 c = x4[(size_t)n * 4 + 2 * qq + 1];
        half8 hh;
        hh[0] = (_Float16)(a.x * di); hh[1] = (_Float16)(a.y * di);
        hh[2] = (_Float16)(a.z * di); hh[3] = (_Float16)(a.w * di);
        hh[4] = (_Float16)(c.x * di); hh[5] = (_Float16)(c.y * di);
        hh[6] = (_Float16)(c.z * di); hh[7] = (_Float16)(c.w * di);
        p0[(size_t)n * 2 + qq] = hh;
    }
}

// ---- fused gather+matmul, quad-grain (no mid-kernel block barrier) ----
// CSR rows start 16B-aligned, so the 8-wide loop loads one ushort8 per iter.
template <int FIN, bool LAST>
__global__ void gmm_kernel(const int* __restrict__ rowstart, const int* __restrict__ rowend,
                           const unsigned short* __restrict__ csr, const half8* __restrict__ p,
                           const float* __restrict__ W, const float* __restrict__ bias,
                           const float* __restrict__ dinv, void* __restrict__ outp) {
    constexpr int F8 = FIN / 8;        // half8 chunks per input row: 2 or 4
    constexpr int LOG2F8 = (FIN == 16) ? 1 : 2;
    constexpr int NOUT4 = 8 / F8;      // float4 output groups per lane: 4 or 2
    __shared__ float4 Ws4[FIN * 8];    // W[FIN][32] as float4
    __shared__ float4 bs4[8];
    int t = threadIdx.x;
    for (int i = t; i < FIN * 8; i += 256) Ws4[i] = ((const float4*)W)[i];
    if (t < 8) bs4[t] = ((const float4*)bias)[t];
    __syncthreads();  // only barrier: before divergent work, no straggler cost

    int f8 = t & (F8 - 1);
    int n = (blockIdx.x * 256 + t) >> LOG2F8;

    // ---- gather stage ----
    half8 self = p[(size_t)n * F8 + f8];
    float acc[8];
#pragma unroll
    for (int e = 0; e < 8; e++) acc[e] = (float)self[e];
    int beg = rowstart[n];  // 16B-aligned (multiple of 8)
    int end = rowend[n];
    int i = beg;
    for (; i + 8 <= end; i += 8) {
        ushort8 sv = *(const ushort8*)(csr + i);  // single dwordx4 load
        half8 a[8];
#pragma unroll
        for (int u = 0; u < 8; u++) a[u] = p[(size_t)sv[u] * F8 + f8];
#pragma unroll
        for (int u = 0; u < 8; u++)
#pragma unroll
            for (int e = 0; e < 8; e++) acc[e] += (float)a[u][e];
    }
    if (i + 4 <= end) {
        int s[4];
#pragma unroll
        for (int u = 0; u < 4; u++) s[u] = csr[i + u];
        half8 a[4];
#pragma unroll
        for (int u = 0; u < 4; u++) a[u] = p[(size_t)s[u] * F8 + f8];
#pragma unroll
        for (int u = 0; u < 4; u++)
#pragma unroll
            for (int e = 0; e < 8; e++) acc[e] += (float)a[u][e];
        i += 4;
    }
    for (; i < end; i++) {
        half8 a = p[(size_t)csr[i] * F8 + f8];
#pragma unroll
        for (int e = 0; e < 8; e++) acc[e] += (float)a[e];
    }

    // ---- in-quad butterfly: lane gains all FIN q-features ----
    float a1[8], a2[8], a3[8];
#pragma unroll
    for (int e = 0; e < 8; e++) a1[e] = __shfl_xor(acc[e], 1);
    if (F8 == 4) {
#pragma unroll
        for (int e = 0; e < 8; e++) a2[e] = __shfl_xor(acc[e], 2);
#pragma unroll
        for (int e = 0; e < 8; e++) a3[e] = __shfl_xor(a1[e], 2);
    }

    // ---- per-lane matmul: outputs [f8*NOUT4*4 .. +NOUT4*4) ----
    int fo0 = f8 * NOUT4;
    float4 o4[NOUT4];
#pragma unroll
    for (int j = 0; j < NOUT4; j++) o4[j] = make_float4(0.f, 0.f, 0.f, 0.f);

#define MM_CHUNK(AR, C)                                               \
    {                                                                 \
        int c_ = (C);                                                 \
        _Pragma("unroll") for (int e = 0; e < 8; e++) {               \
            int fi = c_ * 8 + e;                                      \
            float r = (AR)[e];                                        \
            _Pragma("unroll") for (int j = 0; j < NOUT4; j++) {       \
                float4 wv = Ws4[fi * 8 + fo0 + j];                    \
                o4[j].x += r * wv.x;                                  \
                o4[j].y += r * wv.y;                                  \
                o4[j].z += r * wv.z;                                  \
                o4[j].w += r * wv.w;                                  \
            }                                                         \
        }                                                             \
    }

    MM_CHUNK(acc, f8)
    MM_CHUNK(a1, f8 ^ 1)
    if (F8 == 4) {
        MM_CHUNK(a2, f8 ^ 2)
        MM_CHUNK(a3, f8 ^ 3)
    }
#undef MM_CHUNK

    // ---- epilogue ----
    float di = dinv[n];
    float4 v4[NOUT4];
#pragma unroll
    for (int j = 0; j < NOUT4; j++) {
        float4 bb = bs4[fo0 + j];
        float4 v;
        v.x = o4[j].x * di + bb.x;
        v.y = o4[j].y * di + bb.y;
        v.z = o4[j].z * di + bb.z;
        v.w = o4[j].w * di + bb.w;
        v.x = v.x > 0.f ? v.x : 0.f;
        v.y = v.y > 0.f ? v.y : 0.f;
        v.z = v.z > 0.f ? v.z : 0.f;
        v.w = v.w > 0.f ? v.w : 0.f;
        v4[j] = v;
    }
    if (LAST) {
        float4* o = (float4*)outp;
#pragma unroll
        for (int j = 0; j < NOUT4; j++) o[(size_t)n * 8 + fo0 + j] = v4[j];
    } else {
        half8* o = (half8*)outp;
#pragma unroll
        for (int pr = 0; pr < NOUT4 / 2; pr++) {
            float4 lo = v4[2 * pr], hi = v4[2 * pr + 1];
            half8 hh;
            hh[0] = (_Float16)(lo.x * di); hh[1] = (_Float16)(lo.y * di);
            hh[2] = (_Float16)(lo.z * di); hh[3] = (_Float16)(lo.w * di);
            hh[4] = (_Float16)(hi.x * di); hh[5] = (_Float16)(hi.y * di);
            hh[6] = (_Float16)(hi.z * di); hh[7] = (_Float16)(hi.w * di);
            o[(size_t)n * 4 + fo0 / 2 + pr] = hh;
        }
    }
}

// ---- fc1 partials; graph-split: acc[8] (32 VGPR) for higher occupancy ----
// thread = (kl = t&1 k-half, gh = (t>>1)&1 graph-half, c = t>>2 column).
// Each thread: 64 k-rows (kl + 2*i), 8 graphs (gh*8..+7), one float4 column.
// w/h3 nt (stream-once); part stored cached (read right back by reduce).
__global__ __launch_bounds__(256) void fc1_kernel(const float* __restrict__ h3,
                                                  const float* __restrict__ w,
                                                  float* __restrict__ part) {
    __shared__ float hs[NUM_GRAPHS * FC1_KCHUNK];  // 8 KB
    int t = threadIdx.x;
    int kbase = blockIdx.x * FC1_KCHUNK;
    for (int i = t; i < NUM_GRAPHS * FC1_KCHUNK; i += 256) {
        int g = i >> 7;  // FC1_KCHUNK == 128
        int kk = i & 127;
        hs[i] = ntloadf(h3 + (size_t)g * FC1_IN + kbase + kk);
    }
    __syncthreads();
    int kl = t & 1;         // k-half
    int gh = (t >> 1) & 1;  // graph-half
    int c = t >> 2;         // 0..63: float4 column
    const float* hsg = hs + gh * 8 * FC1_KCHUNK;
    const float4* w4 = (const float4*)w;  // row k = 64 float4
    float4 acc[8];
#pragma unroll
    for (int g = 0; g < 8; g++) acc[g] = make_float4(0.f, 0.f, 0.f, 0.f);

    // rows k = kbase + kl + 2*i, i = 0..63; 4-deep dual banks
    float4 wa[4], wb[4];
#define LOADW(BUF, I0)                                                        \
    _Pragma("unroll") for (int u = 0; u < 4; u++)                             \
        (BUF)[u] = ntload4(&w4[(size_t)(kbase + kl + 2 * ((I0) + u)) * (FC1_OUT / 4) + c]);
#define COMPW(BUF, I0)                                                        \
    _Pragma("unroll") for (int u = 0; u < 4; u++) {                           \
        int kk = kl + 2 * ((I0) + u);                                         \
        _Pragma("unroll") for (int g = 0; g < 8; g++) {                       \
            float hg = hsg[g * FC1_KCHUNK + kk];                              \
            acc[g].x += hg * (BUF)[u].x;                                      \
            acc[g].y += hg * (BUF)[u].y;                                      \
            acc[g].z += hg * (BUF)[u].z;                                      \
            acc[g].w += hg * (BUF)[u].w;                                      \
        }                                                                     \
    }

    LOADW(wa, 0)
    LOADW(wb, 4)
    COMPW(wa, 0)
    LOADW(wa, 8)
    COMPW(wb, 4)
    LOADW(wb, 12)
    COMPW(wa, 8)
    LOADW(wa, 16)
    COMPW(wb, 12)
    LOADW(wb, 20)
    COMPW(wa, 16)
    LOADW(wa, 24)
    COMPW(wb, 20)
    LOADW(wb, 28)
    COMPW(wa, 24)
    LOADW(wa, 32)
    COMPW(wb, 28)
    LOADW(wb, 36)
    COMPW(wa, 32)
    LOADW(wa, 40)
    COMPW(wb, 36)
    LOADW(wb, 44)
    COMPW(wa, 40)
    LOADW(wa, 48)
    COMPW(wb, 44)
    LOADW(wb, 52)
    COMPW(wa, 48)
    LOADW(wa, 56)
    COMPW(wb, 52)
    LOADW(wb, 60)
    COMPW(wa, 56)
    COMPW(wb, 60)
#undef LOADW
#undef COMPW

    // combine the two k-halves (lanes kl and kl^1)
#pragma unroll
    for (int g = 0; g < 8; g++) {
        acc[g].x += __shfl_xor(acc[g].x, 1);
        acc[g].y += __shfl_xor(acc[g].y, 1);
        acc[g].z += __shfl_xor(acc[g].z, 1);
        acc[g].w += __shfl_xor(acc[g].w, 1);
    }
    if (kl == 0) {
        float4* p4 = (float4*)part;
#pragma unroll
        for (int g = 0; g < 8; g++)
            p4[(size_t)blockIdx.x * (NUM_GRAPHS * FC1_OUT / 4) + (gh * 8 + g) * (FC1_OUT / 4) + c] =
                acc[g];
    }
}

// ---- reduce partials -> partial16[bq][j']; 256 blocks; cached loads ----
__global__ void reduce_kernel(const float* __restrict__ part, float* __restrict__ partial16) {
    int tid = blockIdx.x * 256 + threadIdx.x;  // 65536 threads
    int j = tid & 4095;
    int bq = tid >> 12;  // 0..15
    float s = 0.f;
#pragma unroll 8
    for (int u = 0; u < FC1_BLOCKS / RED_Q; u++)
        s += part[(size_t)(bq * (FC1_BLOCKS / RED_Q) + u) * (NUM_GRAPHS * FC1_OUT) + j];
    partial16[bq * (NUM_GRAPHS * FC1_OUT) + j] = s;
}

// ---- fc2: folds the 16 partials, bias+relu, then 256->64 matmul ----
__global__ void fc2_kernel(const float* __restrict__ partial16, const float* __restrict__ fc1_b,
                           const float* __restrict__ w2, const float* __restrict__ b2,
                           float* __restrict__ out) {
    int g = blockIdx.x;
    int j = threadIdx.x;  // 0..63
    __shared__ float vs[FC1_OUT];
    for (int k = j; k < FC1_OUT; k += 64) {
        float s = fc1_b[k];
#pragma unroll
        for (int bq = 0; bq < RED_Q; bq++)
            s += partial16[bq * (NUM_GRAPHS * FC1_OUT) + g * FC1_OUT + k];
        vs[k] = s > 0.f ? s : 0.f;
    }
    __syncthreads();
    float acc = b2[j];
    for (int k = 0; k < FC1_OUT; k++) acc += vs[k] * w2[k * FC2_OUT + j];
    out[g * FC2_OUT + j] = acc;
}

extern "C" void kernel_launch(void* const* d_in, const int* in_sizes, int n_in,
                              void* d_out, int out_size, void* d_ws, size_t ws_size,
                              hipStream_t stream) {
    const float* x = (const float*)d_in[0];
    const int* ei = (const int*)d_in[1];
    const int* src = ei;
    const int* dst = ei + NUM_EDGES;
    const float* W1 = (const float*)d_in[2];
    const float* b1 = (const float*)d_in[3];
    const float* W2 = (const float*)d_in[4];
    const float* b2 = (const float*)d_in[5];
    const float* W3 = (const float*)d_in[6];
    const float* b3 = (const float*)d_in[7];
    const float* fc1_w = (const float*)d_in[8];
    const float* fc1_b = (const float*)d_in[9];
    const float* fc2_w = (const float*)d_in[10];
    const float* fc2_b = (const float*)d_in[11];
    float* out = (float*)d_out;

    // workspace layout (re-poisoned 0xAA each call)
    int* bucket_cursor = (int*)d_ws;                       // 1 KB
    int* binned = bucket_cursor + 256;                     // 5.24 MB
    unsigned short* csr = (unsigned short*)(binned + NB * BUCKET_CAP);  // 4.19 MB
    int* rowstart = (int*)(csr + NB * CSR_CAP);            // 256 KB
    int* rowend = rowstart + N_NODES;                      // 256 KB
    float* dinv = (float*)(rowend + N_NODES);              // 256 KB
    half8* p0 = (half8*)(dinv + N_NODES);                  // N*16 fp16 = 2 MB
    half8* pA = (half8*)(p0 + (size_t)N_NODES * 2);        // N*32 fp16 = 4 MB
    half8* pB = (half8*)(pA + (size_t)N_NODES * 4);        // N*32 fp16 = 4 MB
    float* h3 = (float*)(pB + (size_t)N_NODES * 4);        // N*32 f32 = 8 MB
    float* part = h3 + (size_t)N_NODES * HIDDEN;           // 16 MB
    float* partial16 = part + (size_t)FC1_BLOCKS * NUM_GRAPHS * FC1_OUT;  // 256 KB

    initcur_kernel<<<1, 256, 0, stream>>>(bucket_cursor);
    binA_kernel<<<NUM_EDGES / EPB_A, 256, 0, stream>>>(src, dst, bucket_cursor, binned);
    sortB_kernel<<<NB, 512, 0, stream>>>(bucket_cursor, binned, csr, rowstart, rowend, dinv, x, p0);

    // layer 1: fused gather(16-feat p0) + matmul W1 -> pA (fp16)
    gmm_kernel<IN_FEAT, false><<<N_NODES * 2 / 256, 256, 0, stream>>>(
        rowstart, rowend, csr, p0, W1, b1, dinv, pA);
    // layer 2: fused gather(32-feat pA) + matmul W2 -> pB (fp16)
    gmm_kernel<HIDDEN, false><<<N_NODES * 4 / 256, 256, 0, stream>>>(
        rowstart, rowend, csr, pA, W2, b2, dinv, pB);
    // layer 3: fused gather(32-feat pB) + matmul W3 -> h3 (fp32)
    gmm_kernel<HIDDEN, true><<<N_NODES * 4 / 256, 256, 0, stream>>>(
        rowstart, rowend, csr, pB, W3, b3, dinv, h3);

    fc1_kernel<<<FC1_BLOCKS, 256, 0, stream>>>(h3, fc1_w, part);
    reduce_kernel<<<256, 256, 0, stream>>>(part, partial16);
    fc2_kernel<<<NUM_GRAPHS, 64, 0, stream>>>(partial16, fc1_b, fc2_w, fc2_b, out);
}